// Round 1
// baseline (233.515 us; speedup 1.0000x reference)
//
#include <hip/hip_runtime.h>
#include <math.h>

// SSIM loss, fused: 5 separable 11-tap Gaussian convs + SSIM map + mean.
// Tile 64x32 outputs per 256-thread block; LDS staging with zero-pad halo.

#define KW 11
#define RAD 5
#define TILE_W 64
#define TILE_H 32
#define IN_W (TILE_W + 2 * RAD)   // 74
#define IN_H (TILE_H + 2 * RAD)   // 42
#define S_STRIDE 76               // input stage stride (2-way conflicts max)
#define H_STRIDE 65               // horiz-result stride (breaks 8-row write conflict)
#define IMG_H 512
#define IMG_W 512
#define NPLANES 48                // 16*3
#define TILES_X (IMG_W / TILE_W)  // 8
#define TILES_Y (IMG_H / TILE_H)  // 16
#define NBLOCKS (TILES_X * TILES_Y * NPLANES)  // 6144
#define NPIX (16.0f * 3.0f * 512.0f * 512.0f)

struct GaussW { float g[KW]; };

__global__ __launch_bounds__(256, 2) void ssim_tile(
    const float* __restrict__ img1, const float* __restrict__ img2,
    float* __restrict__ partial, GaussW W)
{
    __shared__ float s1[IN_H][S_STRIDE];
    __shared__ float s2[IN_H][S_STRIDE];
    __shared__ float h[5][IN_H][H_STRIDE];
    __shared__ float red[4];

    const int tid = threadIdx.x;
    const int plane = blockIdx.y;
    const int tile = blockIdx.x;
    const int tx = tile & (TILES_X - 1);
    const int ty = tile >> 3;
    const int c0 = tx * TILE_W;
    const int r0 = ty * TILE_H;
    const float* __restrict__ p1 = img1 + (size_t)plane * IMG_H * IMG_W;
    const float* __restrict__ p2 = img2 + (size_t)plane * IMG_H * IMG_W;

    // ---- stage inputs into LDS with zero padding (matches conv zero-pad) ----
    for (int idx = tid; idx < IN_H * IN_W; idx += 256) {
        int row = idx / IN_W;
        int col = idx - row * IN_W;
        int gr = r0 - RAD + row;
        int gc = c0 - RAD + col;
        float v1 = 0.f, v2 = 0.f;
        if ((unsigned)gr < (unsigned)IMG_H && (unsigned)gc < (unsigned)IMG_W) {
            v1 = p1[gr * IMG_W + gc];
            v2 = p2[gr * IMG_W + gc];
        }
        s1[row][col] = v1;
        s2[row][col] = v2;
    }
    __syncthreads();

    // ---- horizontal pass: h[q][row][c] = sum_j g[j] * q(row, c+j-5) ----
    // thread -> (row = tid>>3 [+32], col group of 8 = tid&7)
    {
        const int cg = (tid & 7) * 8;
        const int row0 = tid >> 3;
        for (int rr = 0; rr < 2; ++rr) {
            const int row = row0 + rr * 32;
            if (row < IN_H) {
                float ax[8]  = {0,0,0,0,0,0,0,0};
                float ay[8]  = {0,0,0,0,0,0,0,0};
                float axx[8] = {0,0,0,0,0,0,0,0};
                float ayy[8] = {0,0,0,0,0,0,0,0};
                float axy[8] = {0,0,0,0,0,0,0,0};
                #pragma unroll
                for (int j = 0; j < 18; ++j) {
                    float x = s1[row][cg + j];
                    float y = s2[row][cg + j];
                    float xx = x * x, yy = y * y, xy = x * y;
                    #pragma unroll
                    for (int o = 0; o < 8; ++o) {
                        const int t = j - o;
                        if (t >= 0 && t < KW) {
                            const float w = W.g[t];
                            ax[o]  += w * x;
                            ay[o]  += w * y;
                            axx[o] += w * xx;
                            ayy[o] += w * yy;
                            axy[o] += w * xy;
                        }
                    }
                }
                #pragma unroll
                for (int o = 0; o < 8; ++o) {
                    const int col = cg + o;
                    h[0][row][col] = ax[o];
                    h[1][row][col] = ay[o];
                    h[2][row][col] = axx[o];
                    h[3][row][col] = ayy[o];
                    h[4][row][col] = axy[o];
                }
            }
        }
    }
    __syncthreads();

    // ---- vertical pass + SSIM map, 8 output rows per thread ----
    // thread -> (col = tid&63, row group = tid>>6)
    const int col = tid & 63;
    const int rbase = (tid >> 6) * 8;
    float ox[8]  = {0,0,0,0,0,0,0,0};
    float oy[8]  = {0,0,0,0,0,0,0,0};
    float oxx[8] = {0,0,0,0,0,0,0,0};
    float oyy[8] = {0,0,0,0,0,0,0,0};
    float oxy[8] = {0,0,0,0,0,0,0,0};
    #pragma unroll
    for (int m = 0; m < 18; ++m) {
        const int hr = rbase + m;
        float vx  = h[0][hr][col];
        float vy  = h[1][hr][col];
        float vxx = h[2][hr][col];
        float vyy = h[3][hr][col];
        float vxy = h[4][hr][col];
        #pragma unroll
        for (int o = 0; o < 8; ++o) {
            const int t = m - o;
            if (t >= 0 && t < KW) {
                const float w = W.g[t];
                ox[o]  += w * vx;
                oy[o]  += w * vy;
                oxx[o] += w * vxx;
                oyy[o] += w * vyy;
                oxy[o] += w * vxy;
            }
        }
    }

    const float C1 = 1.0e-4f;  // (0.01*L)^2
    const float C2 = 9.0e-4f;  // (0.03*L)^2
    float ssum = 0.f;
    #pragma unroll
    for (int o = 0; o < 8; ++o) {
        float mu1 = ox[o], mu2 = oy[o];
        float mu1sq = mu1 * mu1;
        float mu2sq = mu2 * mu2;
        float mu12  = mu1 * mu2;
        float sg1 = oxx[o] - mu1sq;
        float sg2 = oyy[o] - mu2sq;
        float sg12 = oxy[o] - mu12;
        float num = (2.f * mu12 + C1) * (2.f * sg12 + C2);
        float den = (mu1sq + mu2sq + C1) * (sg1 + sg2 + C2);
        ssum += num / den;
    }

    // ---- block reduction -> one partial per block ----
    #pragma unroll
    for (int off = 32; off > 0; off >>= 1)
        ssum += __shfl_down(ssum, off, 64);
    const int lane = tid & 63;
    const int wv = tid >> 6;
    if (lane == 0) red[wv] = ssum;
    __syncthreads();
    if (tid == 0)
        partial[(size_t)blockIdx.y * gridDim.x + blockIdx.x] =
            red[0] + red[1] + red[2] + red[3];
}

__global__ void ssim_finish(const float* __restrict__ partial,
                            float* __restrict__ out)
{
    __shared__ float red[4];
    float s = 0.f;
    for (int i = threadIdx.x; i < NBLOCKS; i += 256) s += partial[i];
    #pragma unroll
    for (int off = 32; off > 0; off >>= 1)
        s += __shfl_down(s, off, 64);
    if ((threadIdx.x & 63) == 0) red[threadIdx.x >> 6] = s;
    __syncthreads();
    if (threadIdx.x == 0) {
        float tot = red[0] + red[1] + red[2] + red[3];
        out[0] = 1.0f - tot / NPIX;
    }
}

extern "C" void kernel_launch(void* const* d_in, const int* in_sizes, int n_in,
                              void* d_out, int out_size, void* d_ws, size_t ws_size,
                              hipStream_t stream) {
    const float* img1 = (const float*)d_in[0];
    const float* img2 = (const float*)d_in[1];
    float* out = (float*)d_out;
    float* partial = (float*)d_ws;

    // Gaussian weights, computed on host (double exp, normalized) — matches
    // reference's np.float32 window to ~1e-8.
    GaussW W;
    double gd[KW], sum = 0.0;
    for (int i = 0; i < KW; ++i) {
        double d = (double)(i - KW / 2);
        gd[i] = exp(-(d * d) / (2.0 * 1.5 * 1.5));
        sum += gd[i];
    }
    for (int i = 0; i < KW; ++i) W.g[i] = (float)(gd[i] / sum);

    dim3 grid(TILES_X * TILES_Y, NPLANES);
    ssim_tile<<<grid, 256, 0, stream>>>(img1, img2, partial, W);
    ssim_finish<<<1, 256, 0, stream>>>(partial, out);
}